// Round 6
// baseline (145.490 us; speedup 1.0000x reference)
//
#include <hip/hip_runtime.h>

typedef unsigned short u16;
typedef unsigned int u32;
typedef _Float16 half8 __attribute__((ext_vector_type(8)));   // MFMA A/B frag
typedef __fp16 fp16x2 __attribute__((ext_vector_type(2)));    // cvt_pkrtz result
typedef __attribute__((ext_vector_type(4))) float floatx4;    // MFMA acc

#define LSTRIDE 72   // u16 per LDS row; rows 16B-aligned, 2-way-max read conflicts

__device__ __forceinline__ u32 pkrtz(float lo, float hi) {
  fp16x2 h = __builtin_amdgcn_cvt_pkrtz(lo, hi);
  return __builtin_bit_cast(u32, h);
}

// ---------------------------------------------------------------------------
// prep: Btg[(p*64+o)][m] = fp16(S * Wpad[m-p][o])  (1024 x 512 u16, row-major)
//       csum_g[o] = sum_c W[c][o]  (fp32)
// Btg is 1 MB -> L2-resident for all gemm blocks. Recomputed every call
// (d_ws is re-poisoned by the harness).
// ---------------------------------------------------------------------------
__global__ __launch_bounds__(256) void prep_kernel(const float* __restrict__ Wm,
                                                   u16* __restrict__ Btg,
                                                   float* __restrict__ csum_g) {
  const int b = blockIdx.x, t = threadIdx.x;
  if (b < 256) {
    int gid = b * 256 + t;
    int o = gid & 63;                 // lane-contiguous -> coalesced W reads
    int m8 = (gid >> 6) & 63;
    int p = gid >> 12;                // 0..15
    const float S = 2.0f / 255.0f;
    float f[8];
    #pragma unroll
    for (int j = 0; j < 8; ++j) {
      int c = m8 * 8 + j - p;
      f[j] = (c >= 0 && c < 496) ? Wm[c * 64 + o] * S : 0.0f;
    }
    uint4 d = uint4{pkrtz(f[0], f[1]), pkrtz(f[2], f[3]),
                    pkrtz(f[4], f[5]), pkrtz(f[6], f[7])};
    *(uint4*)&Btg[(p * 64 + o) * 512 + m8 * 8] = d;   // 16B aligned
  } else {
    __shared__ float red[256];
    int o = t & 63, seg = t >> 6;
    float s = 0.0f;
    for (int c = seg; c < 496; c += 4) s += Wm[c * 64 + o];
    red[t] = s;
    __syncthreads();
    if (t < 64) csum_g[t] = red[t] + red[t + 64] + red[t + 128] + red[t + 192];
  }
}

// ---------------------------------------------------------------------------
// gemm: out[bid][p*8+q][o] = acc - (1024*S+1)*csum[o]
//   acc = sum_m A[(sub,q)][m] * Btg[(p,o)][m]
//   A[(sub,q)][m] = fp16(1024 + window) exact via 0x6400|v, built in-staging.
// BM=128 (16 subs), BN=256, BK=64; grid (128,4); 4 waves 2x2 (M64 x N128).
// Ping-pong register prefetch, fully unrolled kc loop.
// ---------------------------------------------------------------------------
struct Regs {
  int4 a0, a1; int c8;
  uint4 b[8];
};

__global__ __launch_bounds__(256, 2) void gemm_kernel(
    const int* __restrict__ x, const u16* __restrict__ Btg,
    const float* __restrict__ csum_g, float* __restrict__ out) {
  __shared__ __align__(16) u16 As[128 * LSTRIDE];   // 18.4 KB
  __shared__ __align__(16) u16 Bs[256 * LSTRIDE];   // 36.9 KB

  const int t = threadIdx.x;
  const int mtile = blockIdx.x;        // 0..127
  const int n0 = blockIdx.y * 256;     // 0..3

  const int wave = t >> 6, lane = t & 63;
  const int wm = wave >> 1, wn = wave & 1;
  const int quad = lane >> 4, l16 = lane & 15;

  // A staging: thread -> (sub, k-group, q-half)
  const int sA_sub = t >> 4, sA_kg = (t >> 1) & 7, sA_qh = t & 1;
  const long xrow = ((long)mtile * 16 + sA_sub) * 512;
  // B staging: thread -> (row, k-group); 8 passes of 32 rows
  const int sB_row = t >> 3, sB_kg = t & 7;

  floatx4 acc[4][8];
  #pragma unroll
  for (int mt = 0; mt < 4; ++mt)
    #pragma unroll
    for (int nt = 0; nt < 8; ++nt)
      acc[mt][nt] = floatx4{0.f, 0.f, 0.f, 0.f};

  Regs r[2];

  auto loadG = [&](int kc, Regs& R) {
    const int base = kc * 64 + sA_kg * 8;
    R.a0 = *(const int4*)&x[xrow + base];
    R.a1 = *(const int4*)&x[xrow + base + 4];
    R.c8 = (base + 8 < 512) ? x[xrow + base + 8] : 0;  // sub-block zero pad
    const long bbase = (long)(n0 + sB_row) * 512 + kc * 64 + sB_kg * 8;
    #pragma unroll
    for (int pass = 0; pass < 8; ++pass)
      R.b[pass] = *(const uint4*)&Btg[bbase + (long)pass * (32 * 512)];
  };

  auto writeLDS = [&](Regs& R) {
    int c[9] = {R.a0.x, R.a0.y, R.a0.z, R.a0.w,
                R.a1.x, R.a1.y, R.a1.z, R.a1.w, R.c8};
    u32 w16[8];
    #pragma unroll
    for (int j = 0; j < 8; ++j) w16[j] = ((u32)c[j] << 8) | (u32)c[j + 1];
    #pragma unroll
    for (int qi = 0; qi < 4; ++qi) {
      const int q = sA_qh * 4 + qi;
      const int sh = 8 - q;
      u32 d[4];
      #pragma unroll
      for (int jp = 0; jp < 4; ++jp) {
        u32 v0 = (w16[2 * jp] >> sh) & 255u;
        u32 v1 = (w16[2 * jp + 1] >> sh) & 255u;
        d[jp] = v0 | (v1 << 16) | 0x64006400u;       // fp16(1024+v), exact
      }
      *(uint4*)&As[(sA_sub * 8 + q) * LSTRIDE + sA_kg * 8] =
          uint4{d[0], d[1], d[2], d[3]};
    }
    #pragma unroll
    for (int pass = 0; pass < 8; ++pass)
      *(uint4*)&Bs[(sB_row + 32 * pass) * LSTRIDE + sB_kg * 8] = R.b[pass];
  };

  loadG(0, r[0]);
  writeLDS(r[0]);
  __syncthreads();

  #pragma unroll
  for (int kc = 0; kc < 8; ++kc) {
    if (kc < 7) loadG(kc + 1, r[(kc + 1) & 1]);      // in flight over MFMAs

    #pragma unroll
    for (int ks = 0; ks < 2; ++ks) {
      const int koff = ks * 32 + quad * 8;
      half8 af[4], bf[8];
      #pragma unroll
      for (int mt = 0; mt < 4; ++mt)
        af[mt] = *(const half8*)&As[(wm * 64 + mt * 16 + l16) * LSTRIDE + koff];
      #pragma unroll
      for (int nt = 0; nt < 8; ++nt)
        bf[nt] = *(const half8*)&Bs[(wn * 128 + nt * 16 + l16) * LSTRIDE + koff];
      #pragma unroll
      for (int mt = 0; mt < 4; ++mt)
        #pragma unroll
        for (int nt = 0; nt < 8; ++nt)
          acc[mt][nt] = __builtin_amdgcn_mfma_f32_16x16x32_f16(
              af[mt], bf[nt], acc[mt][nt], 0, 0, 0);
    }
    __syncthreads();                   // chunk kc's LDS reads done
    if (kc < 7) {
      writeLDS(r[(kc + 1) & 1]);
      __syncthreads();                 // writes visible
    }
  }

  // epilogue: C/D col=l16, row=quad*4+reg; nt-groups of 4 share one output row
  const float S = 2.0f / 255.0f;
  const float K1 = 1024.0f * S + 1.0f;
  float cs[4];
  #pragma unroll
  for (int j = 0; j < 4; ++j) cs[j] = K1 * csum_g[j * 16 + l16];
  const int pbase = (n0 + wn * 128) >> 6;            // wave-uniform
  #pragma unroll
  for (int mt = 0; mt < 4; ++mt) {
    int mbase = mtile * 128 + wm * 64 + mt * 16 + quad * 4;
    #pragma unroll
    for (int i = 0; i < 4; ++i) {
      int mr = mbase + i;
      int bid = mr >> 3, q = mr & 7;
      float* ob = out + (long)bid * 8192 + q * 64;
      #pragma unroll
      for (int nt = 0; nt < 8; ++nt) {
        int p = pbase + (nt >> 2);
        int o = (nt & 3) * 16 + l16;
        ob[(long)p * 512 + o] = acc[mt][nt][i] - cs[nt & 3];
      }
    }
  }
}

extern "C" void kernel_launch(void* const* d_in, const int* in_sizes, int n_in,
                              void* d_out, int out_size, void* d_ws, size_t ws_size,
                              hipStream_t stream) {
  const int* x = (const int*)d_in[0];        // (256, 4096) byte values as int32
  const float* Wm = (const float*)d_in[1];   // (496, 64) fp32
  float* out = (float*)d_out;                // (256, 8, 128, 64) fp32

  u16* Btg = (u16*)d_ws;                               // 1 MB
  float* csum_g = (float*)((char*)d_ws + (1u << 20));  // 256 B

  prep_kernel<<<dim3(257), dim3(256), 0, stream>>>(Wm, Btg, csum_g);
  gemm_kernel<<<dim3(128, 4), dim3(256), 0, stream>>>(x, Btg, csum_g, out);
}